// Round 4
// baseline (709.548 us; speedup 1.0000x reference)
//
#include <hip/hip_runtime.h>
#include <hip/hip_bf16.h>
#include <cstdint>

// Problem constants: B=4, S=2048, D=1024, H=16, HD=64
static constexpr int Bq  = 4;
static constexpr int Sq  = 2048;
static constexpr int Dq  = 1024;
static constexpr int Hq  = 16;
static constexpr int HDq = 64;
static constexpr int ROWS = Bq * Sq;        // 8192
static constexpr int QKV_N = 3 * Dq;        // 3072

typedef __bf16 bf16x8 __attribute__((ext_vector_type(8)));
typedef __bf16 bf16x4 __attribute__((ext_vector_type(4)));
typedef __bf16 bf16x2 __attribute__((ext_vector_type(2)));
typedef float  floatx4 __attribute__((ext_vector_type(4)));
typedef float  floatx16 __attribute__((ext_vector_type(16)));
typedef unsigned int uintx4 __attribute__((ext_vector_type(4)));

#define MFMA16(a, b, c) __builtin_amdgcn_mfma_f32_16x16x32_bf16((a), (b), (c), 0, 0, 0)
#define MFMA32(a, b, c) __builtin_amdgcn_mfma_f32_32x32x16_bf16((a), (b), (c), 0, 0, 0)

// 0.125 (1/sqrt(HD)) * log2(e): folded into q so softmax uses exp2 directly.
#define QSCALE 0.18033688011112042f

// Async global->LDS 16B copy (global_load_lds_dwordx4).
__device__ __forceinline__ void async16(const void* g, void* l) {
    __builtin_amdgcn_global_load_lds(
        (const __attribute__((address_space(1))) uint32_t*)g,
        (__attribute__((address_space(3))) uint32_t*)l, 16, 0, 0);
}

// ---------------------------------------------------------------------------
// fp32 -> bf16 elementwise convert, 4 elems/thread
__global__ __launch_bounds__(256) void cvt4_kernel(const float4* __restrict__ in,
                                                   bf16x4* __restrict__ out, int n4) {
    int i = blockIdx.x * 256 + threadIdx.x;
    if (i < n4) {
        float4 v = in[i];
        bf16x4 o;
        o[0] = (__bf16)v.x; o[1] = (__bf16)v.y; o[2] = (__bf16)v.z; o[3] = (__bf16)v.w;
        out[i] = o;
    }
}

// fp32 [K,N] -> bf16 transposed [N,K], LDS-tiled 32x32 for coalescing
__global__ __launch_bounds__(256) void tcvt_kernel(const float* __restrict__ in,
                                                   __bf16* __restrict__ out, int K, int N) {
    __shared__ float t[32][33];
    int n0 = blockIdx.x * 32, k0 = blockIdx.y * 32;
    int c = threadIdx.x & 31, r0 = threadIdx.x >> 5;
#pragma unroll
    for (int rr = 0; rr < 32; rr += 8)
        t[r0 + rr][c] = in[(size_t)(k0 + r0 + rr) * N + n0 + c];
    __syncthreads();
#pragma unroll
    for (int rr = 0; rr < 32; rr += 8)
        out[(size_t)(n0 + r0 + rr) * K + k0 + c] = (__bf16)t[c][r0 + rr];
}

// ---------------------------------------------------------------------------
// QKV GEMM: qkv[8192,3072] = xb[8192,1024] @ WqkvT[3072,1024]^T + bqkv.
// 256x256 tile, BK=64, 8 waves (512 thr), 4 phases per K-tile (T3+T4),
// double-buffered LDS (128 KiB), global_load_lds staging with XOR-swizzled
// global source + swizzled ds_read_b128 (rule 21), counted vmcnt(4) once
// per K-tile, raw s_barrier, setprio around MFMA clusters (T5).
// KNOWN LIMIT (R3 post-mortem): 384-block grid at 1 block/CU -> 75%
// round-quantization efficiency; balanced-equivalent ~858 TF matches m248.
__global__ __launch_bounds__(512, 2) void gemm_qkv_kernel(const __bf16* __restrict__ A,
                                                          const __bf16* __restrict__ BT,
                                                          const float* __restrict__ bias,
                                                          __bf16* __restrict__ qkvb,
                                                          __bf16* __restrict__ Vt) {
    // [buf][op(A=0,B=1)][half][row 0..127][col 0..63] bf16 = 128 KiB
    __shared__ __bf16 lds[2][2][2][128][64];

    const int tid  = threadIdx.x;
    const int lane = tid & 63;
    const int wave = tid >> 6;
    const int wm = wave >> 2;            // 0..1 : row half
    const int wn = wave & 3;             // 0..3 : 64-col group
    const int l31 = lane & 31;
    const int hi  = lane >> 5;
    const int kx  = l31 & 7;             // row XOR key for LDS swizzle

    const int m0 = blockIdx.y * 256;
    const int n0 = blockIdx.x * 256;

    const int srow = lane >> 3;                       // 0..7
    const int ssl  = ((lane & 7) ^ srow) * 8;         // swizzled elem offset
    const __bf16* gA = A  + (size_t)(m0 + wave * 16 + srow) * 1024 + ssl;
    const __bf16* gB = BT + (size_t)(n0 + wave * 16 + srow) * 1024 + ssl;

    auto STAGE = [&](int buf, int op, int half, int ktel) {
        const __bf16* g = (op ? gB : gA) + (size_t)half * (128 * 1024) + ktel;
        __bf16* l = &lds[buf][op][half][0][0] + wave * 1024 + lane * 8;
        async16(g, l);                    // rows w*16 .. +7
        async16(g + 8 * 1024, l + 512);   // rows w*16+8 .. +15
    };

    floatx16 acc[4][2] = {};   // [fm][fn] 32x32 frags

    // Prologue: t0 fully + first halves of t1 (order mimics steady state).
    STAGE(0, 1, 0, 0);    // B-h0(t0)
    STAGE(0, 0, 0, 0);    // A-h0(t0)
    STAGE(0, 1, 1, 0);    // B-h1(t0)
    STAGE(0, 0, 1, 0);    // A-h1(t0)
    STAGE(1, 1, 0, 64);   // B-h0(t1)
    STAGE(1, 0, 0, 64);   // A-h0(t1)
    asm volatile("s_waitcnt vmcnt(4)" ::: "memory");  // t0's 4 halves landed
    __builtin_amdgcn_sched_barrier(0);
    __builtin_amdgcn_s_barrier();

    const int brow = (wn & 1) * 64;

    for (int t = 0; t < 16; ++t) {
        const int d = t & 1;
        const __bf16* As = &lds[d][0][wm][0][0];
        const __bf16* Bs = &lds[d][1][wn >> 1][0][0];

        bf16x8 af[2][4], bf0[4], bf1[4];

        // ---- P1: read A(fm0,1)+B(fn0); stage B-h1(t+1); MFMA C[0][0],C[1][0]
#pragma unroll
        for (int mf = 0; mf < 2; ++mf)
#pragma unroll
            for (int ks = 0; ks < 4; ++ks)
                af[mf][ks] = *(const bf16x8*)(As + (mf * 32 + l31) * 64 + ((ks * 2 + hi) ^ kx) * 8);
#pragma unroll
        for (int ks = 0; ks < 4; ++ks)
            bf0[ks] = *(const bf16x8*)(Bs + (brow + l31) * 64 + ((ks * 2 + hi) ^ kx) * 8);
        if (t + 1 < 16) STAGE(d ^ 1, 1, 1, (t + 1) * 64);
        __builtin_amdgcn_s_barrier();
        __builtin_amdgcn_s_setprio(1);
#pragma unroll
        for (int ks = 0; ks < 4; ++ks) {
            acc[0][0] = MFMA32(af[0][ks], bf0[ks], acc[0][0]);
            acc[1][0] = MFMA32(af[1][ks], bf0[ks], acc[1][0]);
        }
        __builtin_amdgcn_s_setprio(0);
        __builtin_amdgcn_s_barrier();

        // ---- P2: read B(fn1); stage A-h1(t+1); MFMA C[0][1],C[1][1]
#pragma unroll
        for (int ks = 0; ks < 4; ++ks)
            bf1[ks] = *(const bf16x8*)(Bs + (brow + 32 + l31) * 64 + ((ks * 2 + hi) ^ kx) * 8);
        if (t + 1 < 16) STAGE(d ^ 1, 0, 1, (t + 1) * 64);
        __builtin_amdgcn_s_barrier();
        __builtin_amdgcn_s_setprio(1);
#pragma unroll
        for (int ks = 0; ks < 4; ++ks) {
            acc[0][1] = MFMA32(af[0][ks], bf1[ks], acc[0][1]);
            acc[1][1] = MFMA32(af[1][ks], bf1[ks], acc[1][1]);
        }
        __builtin_amdgcn_s_setprio(0);
        __builtin_amdgcn_s_barrier();

        // ---- P3: read A(fm2,3); stage B-h0(t+2); MFMA C[2][1],C[3][1]
#pragma unroll
        for (int mf = 0; mf < 2; ++mf)
#pragma unroll
            for (int ks = 0; ks < 4; ++ks)
                af[mf][ks] = *(const bf16x8*)(As + ((2 + mf) * 32 + l31) * 64 + ((ks * 2 + hi) ^ kx) * 8);
        if (t + 2 < 16) STAGE(d, 1, 0, (t + 2) * 64);
        __builtin_amdgcn_s_barrier();
        __builtin_amdgcn_s_setprio(1);
#pragma unroll
        for (int ks = 0; ks < 4; ++ks) {
            acc[2][1] = MFMA32(af[0][ks], bf1[ks], acc[2][1]);
            acc[3][1] = MFMA32(af[1][ks], bf1[ks], acc[3][1]);
        }
        __builtin_amdgcn_s_setprio(0);
        __builtin_amdgcn_s_barrier();

        // ---- P4: stage A-h0(t+2); MFMA C[2][0],C[3][0]; counted vmcnt
        if (t + 2 < 16) STAGE(d, 0, 0, (t + 2) * 64);
        __builtin_amdgcn_s_barrier();
        __builtin_amdgcn_s_setprio(1);
#pragma unroll
        for (int ks = 0; ks < 4; ++ks) {
            acc[2][0] = MFMA32(af[0][ks], bf0[ks], acc[2][0]);
            acc[3][0] = MFMA32(af[1][ks], bf0[ks], acc[3][0]);
        }
        __builtin_amdgcn_s_setprio(0);
        if (t < 14) {
            asm volatile("s_waitcnt vmcnt(4)" ::: "memory");
        } else {
            asm volatile("s_waitcnt vmcnt(0)" ::: "memory");
        }
        __builtin_amdgcn_sched_barrier(0);
        __builtin_amdgcn_s_barrier();
    }

    // Epilogue. C 32x32 layout: col=l31, row=(r&3)+8*(r>>2)+4*hi.
#pragma unroll
    for (int fn = 0; fn < 2; ++fn) {
        const int cg = n0 + wn * 64 + fn * 32;   // frag col group (32 cols)
        const int cm = cg % 192;                 // 0,32=q 64,96=k 128,160=v
        const float bv = bias[cg + l31];
        if (cm >= 128) {
            // v-chunk -> Vt[b][h][d][s], bf16x4 along s
            const int hh = cg / 192;
            const int dd = cm - 128 + l31;
            const int bb = m0 >> 11;
            const int sb = (m0 + wm * 128) & 2047;
            __bf16* vt = Vt + ((size_t)(bb * Hq + hh) * HDq + dd) * Sq + sb;
#pragma unroll
            for (int fm = 0; fm < 4; ++fm)
#pragma unroll
                for (int g = 0; g < 4; ++g) {
                    bf16x4 vv;
#pragma unroll
                    for (int i = 0; i < 4; ++i) vv[i] = (__bf16)(acc[fm][fn][g * 4 + i] + bv);
                    *(bf16x4*)(vt + fm * 32 + g * 8 + hi * 4) = vv;
                }
        } else {
            const float sc = (cm < 64) ? QSCALE : 1.0f;
#pragma unroll
            for (int fm = 0; fm < 4; ++fm)
#pragma unroll
                for (int r = 0; r < 16; ++r) {
                    int m = m0 + wm * 128 + fm * 32 + (r & 3) + 8 * (r >> 2) + 4 * hi;
                    qkvb[(size_t)m * QKV_N + cg + l31] = (__bf16)((acc[fm][fn][r] + bv) * sc);
                }
        }
    }
}

// ---------------------------------------------------------------------------
// C[M,N] = A[M,K] @ BT[N,K]^T + bias[N]  (m97-ladder structure, f32 out).
__global__ __launch_bounds__(256) void gemm_out_kernel(const __bf16* __restrict__ A,
                                                       const __bf16* __restrict__ BT,
                                                       const float* __restrict__ bias,
                                                       float* __restrict__ Cout,
                                                       int M, int N, int K) {
    __shared__ __bf16 As[128 * 32];
    __shared__ __bf16 Bs[128 * 32];

    const int t = threadIdx.x;
    const int lane = t & 63;
    const int wave = t >> 6;
    const int wm = wave & 1, wn = wave >> 1;
    const int l15 = lane & 15;
    const int kg = (lane >> 4) * 8;

    const int m0 = blockIdx.y * 128;
    const int n0 = blockIdx.x * 128;

    const int srow = t >> 2;
    const int scol = (t & 3) * 8;
    const __bf16* ag = A  + (size_t)(m0 + srow) * K + scol;
    const __bf16* bg = BT + (size_t)(n0 + srow) * K + scol;
    __bf16* al = As + t * 8;
    __bf16* bl = Bs + t * 8;

    floatx4 acc[4][4] = {};

    for (int k0 = 0; k0 < K; k0 += 32) {
        __syncthreads();
        async16(ag + k0,                    al);
        async16(ag + (size_t)64 * K + k0,   al + 2048);
        async16(bg + k0,                    bl);
        async16(bg + (size_t)64 * K + k0,   bl + 2048);
        __syncthreads();

        bf16x8 af[4], bfr[4];
#pragma unroll
        for (int mi = 0; mi < 4; ++mi)
            af[mi] = *(const bf16x8*)(As + (wm * 64 + mi * 16 + l15) * 32 + kg);
#pragma unroll
        for (int ni = 0; ni < 4; ++ni)
            bfr[ni] = *(const bf16x8*)(Bs + (wn * 64 + ni * 16 + l15) * 32 + kg);
#pragma unroll
        for (int mi = 0; mi < 4; ++mi)
#pragma unroll
            for (int ni = 0; ni < 4; ++ni)
                acc[mi][ni] = MFMA16(af[mi], bfr[ni], acc[mi][ni]);
    }

    // C/D layout: col = lane&15, row = (lane>>4)*4 + reg   [verified m89/m91]
    const int r0 = (lane >> 4) * 4;
    const int wn0 = n0 + wn * 64;

#pragma unroll
    for (int ni = 0; ni < 4; ++ni) {
        int col = wn0 + ni * 16 + l15;
        float bv = bias[col];
#pragma unroll
        for (int mi = 0; mi < 4; ++mi) {
#pragma unroll
            for (int i = 0; i < 4; ++i) {
                int row = m0 + wm * 64 + mi * 16 + r0 + i;
                Cout[(size_t)row * N + col] = acc[mi][ni][i] + bv;
            }
        }
    }
}

// ---------------------------------------------------------------------------
// Flash attention, 32x32-MFMA transposed compute (S^T = K Q^T, O^T = V^T P^T),
// max-free softmax (q pre-scaled by 0.125*log2e -> p = exp2(s)).
// Wave owns 64 q rows; block = (b,h) x 256 q rows x (1/NS of the keys).
//
// NS=2 (split-K, R4): keys [s*1024,(s+1)*1024) per block; since softmax is
// max-free, partials are EXACTLY summable: O = (O0+O1)/(l0+l1). Blocks write
// raw f32 O-partials + l-sums; combine_kernel normalizes. Grid 1024 blocks
// -> 4 blocks/CU -> 4 waves/SIMD (vs 2 at NS=1): the R3 counters showed the
// kernel <30% issue-utilized and latency-bound at 2 waves/SIMD.
// NS=1: fallback path (identical to R3) when workspace can't hold partials.
template <int NS>
__global__ __launch_bounds__(256, 4) void attn_kernel(const __bf16* __restrict__ qkv,
                                                      const __bf16* __restrict__ Vt,
                                                      __bf16* __restrict__ v2,
                                                      float* __restrict__ Opart,
                                                      float* __restrict__ Lpart) {
    const int bh = blockIdx.x / NS;
    const int sp = (NS > 1) ? (blockIdx.x % NS) : 0;
    const int b = bh >> 4, h = bh & 15;
    const int q0 = blockIdx.y * 256;
    const int tid  = threadIdx.x;
    const int lane = tid & 63;
    const int wave = tid >> 6;
    const int l31  = lane & 31;
    const int hi   = lane >> 5;          // half-wave index
    const int kx   = l31 & 7;            // row XOR key for LDS swizzle
    const size_t rs = QKV_N;
    const __bf16* base  = qkv + (size_t)b * Sq * rs + (size_t)h * (3 * HDq);
    const __bf16* vbase = Vt + (size_t)bh * HDq * Sq;

    __shared__ alignas(16) __bf16 Ks[2][64][64];   // [buf][key][d]   (swizzled)
    __shared__ alignas(16) __bf16 Vs[2][64][64];   // [buf][d][key]   (swizzled)

    // Q B-frags, two 32-q groups: lane holds Q[q][d = hi*8 + j + st*16]
    bf16x8 qb[2][4];
#pragma unroll
    for (int qg = 0; qg < 2; ++qg) {
        const __bf16* qr = base + (size_t)(q0 + wave * 64 + qg * 32 + l31) * rs + hi * 8;
#pragma unroll
        for (int st = 0; st < 4; ++st) qb[qg][st] = *(const bf16x8*)(qr + st * 16);
    }

    // Staging map: wave-issue covers 8 rows x 64 cols (1 KiB); lane ->
    // (row = base+lane/8, slot = lane&7). LDS dest is linear (base+lane*16);
    // the XOR swizzle lives in the GLOBAL source slot: slot ^ (row&7).
    const int rA = wave * 8 + (lane >> 3);          // rows 0..31
    const int rB = rA + 32;                         // rows 32..63 (same &7)
    const int sw = ((lane & 7) ^ (rA & 7)) * 8;     // pre-swizzled elem offset
    const __bf16* gK0 = base + HDq + (size_t)rA * rs + sw;
    const __bf16* gK1 = base + HDq + (size_t)rB * rs + sw;
    const __bf16* gV0 = vbase + (size_t)rA * Sq + sw;
    const __bf16* gV1 = vbase + (size_t)rB * Sq + sw;
    const int loff0 = wave * 512 + lane * 8;        // elem offsets into a buf
    const int loff1 = (4 + wave) * 512 + lane * 8;

    auto STAGE = [&](int bufi, int kt) {
        const size_t ko = (size_t)kt * rs;
        async16(gK0 + ko, &Ks[bufi][0][0] + loff0);
        async16(gK1 + ko, &Ks[bufi][0][0] + loff1);
        async16(gV0 + kt, &Vs[bufi][0][0] + loff0);
        async16(gV1 + kt, &Vs[bufi][0][0] + loff1);
    };

    // exp2 + bf16 pack + permlane regroup: c (16 scores) -> 2 PV B-frags.
    auto softmax_pb = [&](const floatx16& c, float& la, bf16x8* pb) {
        unsigned int W[8];
        float s0 = 0.f, s1 = 0.f;
#pragma unroll
        for (int m = 0; m < 8; ++m) {
            float e0 = __builtin_amdgcn_exp2f(c[2 * m]);
            float e1 = __builtin_amdgcn_exp2f(c[2 * m + 1]);
            s0 += e0; s1 += e1;              // two independent add chains
            union { bf16x2 v; unsigned int u; } pk;
            pk.v[0] = (__bf16)e0; pk.v[1] = (__bf16)e1;
            W[m] = pk.u;
        }
        la += s0 + s1;
#pragma unroll
        for (int ks = 0; ks < 2; ++ks) {
            auto r0 = __builtin_amdgcn_permlane32_swap(W[ks * 4 + 0], W[ks * 4 + 2], false, false);
            auto r1 = __builtin_amdgcn_permlane32_swap(W[ks * 4 + 1], W[ks * 4 + 3], false, false);
            uintx4 bb; bb[0] = r0[0]; bb[1] = r1[0]; bb[2] = r0[1]; bb[3] = r1[1];
            pb[ks] = __builtin_bit_cast(bf16x8, bb);
        }
    };

    floatx16 o[2][2] = {};   // [qg][d-half]: O^T d rows 0..31 / 32..63, col q
    float la0 = 0.f, la1 = 0.f;

    const int kbeg = sp * (Sq / NS);
    const int kend = kbeg + Sq / NS;

    STAGE(0, kbeg);
    __syncthreads();             // compiler drains vmcnt before s_barrier

    int cur = 0;
    for (int kt = kbeg; kt < kend; kt += 64, cur ^= 1) {
        if (kt + 64 < kend) STAGE(cur ^ 1, kt + 64);  // in flight across compute

#pragma unroll
        for (int half = 0; half < 2; ++half) {
            const int key = half * 32 + l31;        // A-frag row (key&7 == kx)

            // S^T = K Q^T : each K A-frag read feeds both q-groups
            floatx16 c0 = {}, c1 = {};
#pragma unroll
            for (int st = 0; st < 4; ++st) {
                bf16x8 a = *(const bf16x8*)(&Ks[cur][key][((st * 2 + hi) ^ kx) * 8]);
                c0 = MFMA32(a, qb[0][st], c0);
                c1 = MFMA32(a, qb[1][st], c1);
            }

            bf16x8 pb0[2], pb1[2];
            softmax_pb(c0, la0, pb0);
            softmax_pb(c1, la1, pb1);

            // O^T += V^T P^T : each V A-frag read feeds both q-groups
#pragma unroll
            for (int ks = 0; ks < 2; ++ks) {
                const int kslot = half * 4 + ks * 2 + hi;  // 16B key-slot 0..7
                bf16x8 va0 = *(const bf16x8*)(&Vs[cur][l31][(kslot ^ kx) * 8]);
                bf16x8 va1 = *(const bf16x8*)(&Vs[cur][32 + l31][(kslot ^ kx) * 8]);
                o[0][0] = MFMA32(va0, pb0[ks], o[0][0]);
                o[0][1] = MFMA32(va1, pb0[ks], o[0][1]);
                o[1][0] = MFMA32(va0, pb1[ks], o[1][0]);
                o[1][1] = MFMA32(va1, pb1[ks], o[1][1]);
            }
        }
        __syncthreads();  // drains stage vmcnt; protects buf reuse
    }

    // l reduction: lanes l and l^32 hold the two key-halves of the same q.
    // O^T C-layout: col q=l31, row d = (reg&3)+8*(reg>>2)+4*hi.
#pragma unroll
    for (int qg = 0; qg < 2; ++qg) {
        float lsum = qg ? la1 : la0;
        float l = lsum + __shfl_xor(lsum, 32);
        const int q = q0 + wave * 64 + qg * 32 + l31;

        if (NS == 1) {
            // Direct write. Quirk: v2[b*2048 + h*128 + q/16][(q%16)*64 + d]
            float rinv = 1.0f / l;
            size_t row = (size_t)b * Sq + h * 128 + (q >> 4);
            __bf16* vrow = v2 + row * Dq + (size_t)(q & 15) * 64;
#pragma unroll
            for (int gg = 0; gg < 4; ++gg) {
                bf16x4 ov;
#pragma unroll
                for (int i = 0; i < 4; ++i) ov[i] = (__bf16)(o[qg][0][gg * 4 + i] * rinv);
                *(bf16x4*)(vrow + gg * 8 + hi * 4) = ov;
#pragma unroll
                for (int i = 0; i < 4; ++i) ov[i] = (__bf16)(o[qg][1][gg * 4 + i] * rinv);
                *(bf16x4*)(vrow + 32 + gg * 8 + hi * 4) = ov;
            }
        } else {
            // Raw f32 partials: Opart[sp][bh*2048+q][d], Lpart[sp][bh*2048+q]
            const size_t ql = (size_t)bh * Sq + q;
            if (hi == 0) Lpart[(size_t)sp * (64 * Sq) + ql] = l;
            float* orow = Opart + ((size_t)sp * (64 * Sq) + ql) * HDq;
#pragma unroll
            for (int gg = 0; gg < 4; ++gg) {
                float4 f0, f1;
                f0.x = o[qg][0][gg * 4 + 0]; f0.y = o[qg][0][gg * 4 + 1];
                f0.z = o[qg][0][gg * 4 + 2]; f0.w = o[qg][0][gg * 4 + 3];
                f1.x = o[qg][1][gg * 4 + 0]; f1.y = o[qg][1][gg * 4 + 1];
                f1.z = o[qg][1][gg * 4 + 2]; f1.w = o[qg][1][gg * 4 + 3];
                *(float4*)(orow + gg * 8 + hi * 4)      = f0;
                *(float4*)(orow + 32 + gg * 8 + hi * 4) = f1;
            }
        }
    }
}

// ---------------------------------------------------------------------------
// Split-K combine: v2 = (O0+O1) / (l0+l1), quirk-reshaped.
// One float4 per thread; 2,097,152 float4s per split.
__global__ __launch_bounds__(256) void combine_kernel(const float4* __restrict__ O,
                                                      const float* __restrict__ L,
                                                      __bf16* __restrict__ v2) {
    const int idx = blockIdx.x * 256 + threadIdx.x;   // 0 .. 2097151 (exact)
    const int d4 = idx & 15;
    const int ql = idx >> 4;          // bh*2048 + q, 0..131071
    float4 a = O[idx];
    float4 c = O[2097152 + idx];
    float rinv = 1.0f / (L[ql] + L[131072 + ql]);
    const int bh = ql >> 11, q = ql & 2047;
    const int b = bh >> 4, h = bh & 15;
    __bf16* dst = v2 + ((size_t)(b * Sq + h * 128 + (q >> 4))) * Dq
                     + (size_t)(q & 15) * 64 + d4 * 4;
    bf16x4 o;
    o[0] = (__bf16)((a.x + c.x) * rinv);
    o[1] = (__bf16)((a.y + c.y) * rinv);
    o[2] = (__bf16)((a.z + c.z) * rinv);
    o[3] = (__bf16)((a.w + c.w) * rinv);
    *(bf16x4*)dst = o;
}

// ---------------------------------------------------------------------------
extern "C" void kernel_launch(void* const* d_in, const int* in_sizes, int n_in,
                              void* d_out, int out_size, void* d_ws, size_t ws_size,
                              hipStream_t stream) {
    const float* x    = (const float*)d_in[0];  // [4,2048,1024]
    const float* Wqkv = (const float*)d_in[1];  // [1024,3072]
    const float* bqkv = (const float*)d_in[2];  // [3072]
    const float* Wo   = (const float*)d_in[3];  // [1024,1024]
    const float* bo   = (const float*)d_in[4];  // [1024]
    float* out = (float*)d_out;                 // [4,2048,1024] f32

    __bf16* xb    = (__bf16*)d_ws;                        // 8192*1024
    __bf16* WqkvT = xb    + (size_t)ROWS * Dq;            // 3072*1024
    __bf16* WoT   = WqkvT + (size_t)QKV_N * Dq;           // 1024*1024
    __bf16* qkvb  = WoT   + (size_t)Dq * Dq;              // 8192*3072
    __bf16* Vt    = qkvb  + (size_t)ROWS * QKV_N;         // 64*64*2048
    __bf16* v2    = xb;                                   // alias (xb dead)
    float*  Opart = (float*)(Vt + (size_t)Bq * Hq * HDq * Sq);  // 2*131072*64 f32
    float*  Lpart = Opart + (size_t)2 * 131072 * 64;            // 2*131072 f32

    const size_t need = (size_t)((char*)(Lpart + 2 * 131072) - (char*)d_ws);
    const bool use_split = ws_size >= need;

    const int nx4 = ROWS * Dq / 4;
    cvt4_kernel<<<(nx4 + 255) / 256, 256, 0, stream>>>((const float4*)x, (bf16x4*)xb, nx4);
    tcvt_kernel<<<dim3(QKV_N / 32, Dq / 32), 256, 0, stream>>>(Wqkv, WqkvT, Dq, QKV_N);
    tcvt_kernel<<<dim3(Dq / 32, Dq / 32), 256, 0, stream>>>(Wo, WoT, Dq, Dq);

    gemm_qkv_kernel<<<dim3(QKV_N / 256, ROWS / 256), 512, 0, stream>>>(
        xb, WqkvT, bqkv, qkvb, Vt);

    if (use_split) {
        attn_kernel<2><<<dim3(Bq * Hq * 2, Sq / 256), 256, 0, stream>>>(
            qkvb, Vt, nullptr, Opart, Lpart);
        combine_kernel<<<2097152 / 256, 256, 0, stream>>>(
            (const float4*)Opart, Lpart, v2);
    } else {
        attn_kernel<1><<<dim3(Bq * Hq, Sq / 256), 256, 0, stream>>>(
            qkvb, Vt, v2, nullptr, nullptr);
    }

    gemm_out_kernel<<<dim3(Dq / 128, ROWS / 128), 256, 0, stream>>>(
        v2, WoT, bo, out, ROWS, Dq, Dq);
}

// Round 5
// 269.577 us; speedup vs baseline: 2.6321x; 2.6321x over previous
//
#include <hip/hip_runtime.h>
#include <hip/hip_bf16.h>
#include <cstdint>

// Problem constants: B=4, S=2048, D=1024, H=16, HD=64
static constexpr int Bq  = 4;
static constexpr int Sq  = 2048;
static constexpr int Dq  = 1024;
static constexpr int Hq  = 16;
static constexpr int HDq = 64;
static constexpr int ROWS = Bq * Sq;        // 8192
static constexpr int QKV_N = 3 * Dq;        // 3072

typedef __bf16 bf16x8 __attribute__((ext_vector_type(8)));
typedef __bf16 bf16x4 __attribute__((ext_vector_type(4)));
typedef __bf16 bf16x2 __attribute__((ext_vector_type(2)));
typedef float  floatx4 __attribute__((ext_vector_type(4)));
typedef float  floatx16 __attribute__((ext_vector_type(16)));
typedef unsigned int uintx4 __attribute__((ext_vector_type(4)));

#define MFMA16(a, b, c) __builtin_amdgcn_mfma_f32_16x16x32_bf16((a), (b), (c), 0, 0, 0)
#define MFMA32(a, b, c) __builtin_amdgcn_mfma_f32_32x32x16_bf16((a), (b), (c), 0, 0, 0)

// 0.125 (1/sqrt(HD)) * log2(e): folded into q so softmax uses exp2 directly.
#define QSCALE 0.18033688011112042f

// Async global->LDS 16B copy (global_load_lds_dwordx4).
__device__ __forceinline__ void async16(const void* g, void* l) {
    __builtin_amdgcn_global_load_lds(
        (const __attribute__((address_space(1))) uint32_t*)g,
        (__attribute__((address_space(3))) uint32_t*)l, 16, 0, 0);
}

// ---------------------------------------------------------------------------
// Fused prep: fp32->bf16 convert of x (blocks [0,8192)), Wqkv transpose-cvt
// (blocks [8192,11264)), Wo transpose-cvt (blocks [11264,12288)).
// One launch instead of three.
__global__ __launch_bounds__(256) void prep_kernel(const float4* __restrict__ x4,
                                                   bf16x4* __restrict__ xb4,
                                                   const float* __restrict__ Wqkv,
                                                   __bf16* __restrict__ WqkvT,
                                                   const float* __restrict__ Wo,
                                                   __bf16* __restrict__ WoT) {
    __shared__ float t[32][33];
    const int bx = blockIdx.x;
    if (bx < 8192) {
        int i = bx * 256 + threadIdx.x;      // 8192*256 == ROWS*Dq/4 exactly
        float4 v = x4[i];
        bf16x4 o;
        o[0] = (__bf16)v.x; o[1] = (__bf16)v.y; o[2] = (__bf16)v.z; o[3] = (__bf16)v.w;
        xb4[i] = o;
        return;
    }
    const float* in; __bf16* out; int K, N, bid;
    if (bx < 8192 + 3072) { bid = bx - 8192;  in = Wqkv; out = WqkvT; K = Dq; N = QKV_N; }
    else                  { bid = bx - 11264; in = Wo;   out = WoT;   K = Dq; N = Dq; }
    const int nt = N / 32;
    const int n0 = (bid % nt) * 32, k0 = (bid / nt) * 32;
    const int c = threadIdx.x & 31, r0 = threadIdx.x >> 5;
#pragma unroll
    for (int rr = 0; rr < 32; rr += 8)
        t[r0 + rr][c] = in[(size_t)(k0 + r0 + rr) * N + n0 + c];
    __syncthreads();
#pragma unroll
    for (int rr = 0; rr < 32; rr += 8)
        out[(size_t)(n0 + r0 + rr) * K + k0 + c] = (__bf16)t[c][r0 + rr];
}

// ---------------------------------------------------------------------------
// QKV GEMM: qkv[8192,3072] = xb[8192,1024] @ WqkvT[3072,1024]^T + bqkv.
// 256x256 tile, BK=64, 8 waves (512 thr), 4 phases per K-tile (T3+T4),
// double-buffered LDS (128 KiB), global_load_lds staging with XOR-swizzled
// global source + swizzled ds_read_b128 (rule 21), counted vmcnt(4) once
// per K-tile, raw s_barrier, setprio around MFMA clusters (T5).
// KNOWN LIMIT (R3 post-mortem): 384-block grid at 1 block/CU -> 75%
// round-quantization efficiency; balanced-equivalent ~858 TF matches m248.
__global__ __launch_bounds__(512, 2) void gemm_qkv_kernel(const __bf16* __restrict__ A,
                                                          const __bf16* __restrict__ BT,
                                                          const float* __restrict__ bias,
                                                          __bf16* __restrict__ qkvb,
                                                          __bf16* __restrict__ Vt) {
    // [buf][op(A=0,B=1)][half][row 0..127][col 0..63] bf16 = 128 KiB
    __shared__ __bf16 lds[2][2][2][128][64];

    const int tid  = threadIdx.x;
    const int lane = tid & 63;
    const int wave = tid >> 6;
    const int wm = wave >> 2;            // 0..1 : row half
    const int wn = wave & 3;             // 0..3 : 64-col group
    const int l31 = lane & 31;
    const int hi  = lane >> 5;
    const int kx  = l31 & 7;             // row XOR key for LDS swizzle

    const int m0 = blockIdx.y * 256;
    const int n0 = blockIdx.x * 256;

    const int srow = lane >> 3;                       // 0..7
    const int ssl  = ((lane & 7) ^ srow) * 8;         // swizzled elem offset
    const __bf16* gA = A  + (size_t)(m0 + wave * 16 + srow) * 1024 + ssl;
    const __bf16* gB = BT + (size_t)(n0 + wave * 16 + srow) * 1024 + ssl;

    auto STAGE = [&](int buf, int op, int half, int ktel) {
        const __bf16* g = (op ? gB : gA) + (size_t)half * (128 * 1024) + ktel;
        __bf16* l = &lds[buf][op][half][0][0] + wave * 1024 + lane * 8;
        async16(g, l);                    // rows w*16 .. +7
        async16(g + 8 * 1024, l + 512);   // rows w*16+8 .. +15
    };

    floatx16 acc[4][2] = {};   // [fm][fn] 32x32 frags

    // Prologue: t0 fully + first halves of t1 (order mimics steady state).
    STAGE(0, 1, 0, 0);    // B-h0(t0)
    STAGE(0, 0, 0, 0);    // A-h0(t0)
    STAGE(0, 1, 1, 0);    // B-h1(t0)
    STAGE(0, 0, 1, 0);    // A-h1(t0)
    STAGE(1, 1, 0, 64);   // B-h0(t1)
    STAGE(1, 0, 0, 64);   // A-h0(t1)
    asm volatile("s_waitcnt vmcnt(4)" ::: "memory");  // t0's 4 halves landed
    __builtin_amdgcn_sched_barrier(0);
    __builtin_amdgcn_s_barrier();

    const int brow = (wn & 1) * 64;

    for (int t = 0; t < 16; ++t) {
        const int d = t & 1;
        const __bf16* As = &lds[d][0][wm][0][0];
        const __bf16* Bs = &lds[d][1][wn >> 1][0][0];

        bf16x8 af[2][4], bf0[4], bf1[4];

        // ---- P1: read A(fm0,1)+B(fn0); stage B-h1(t+1); MFMA C[0][0],C[1][0]
#pragma unroll
        for (int mf = 0; mf < 2; ++mf)
#pragma unroll
            for (int ks = 0; ks < 4; ++ks)
                af[mf][ks] = *(const bf16x8*)(As + (mf * 32 + l31) * 64 + ((ks * 2 + hi) ^ kx) * 8);
#pragma unroll
        for (int ks = 0; ks < 4; ++ks)
            bf0[ks] = *(const bf16x8*)(Bs + (brow + l31) * 64 + ((ks * 2 + hi) ^ kx) * 8);
        if (t + 1 < 16) STAGE(d ^ 1, 1, 1, (t + 1) * 64);
        __builtin_amdgcn_s_barrier();
        __builtin_amdgcn_s_setprio(1);
#pragma unroll
        for (int ks = 0; ks < 4; ++ks) {
            acc[0][0] = MFMA32(af[0][ks], bf0[ks], acc[0][0]);
            acc[1][0] = MFMA32(af[1][ks], bf0[ks], acc[1][0]);
        }
        __builtin_amdgcn_s_setprio(0);
        __builtin_amdgcn_s_barrier();

        // ---- P2: read B(fn1); stage A-h1(t+1); MFMA C[0][1],C[1][1]
#pragma unroll
        for (int ks = 0; ks < 4; ++ks)
            bf1[ks] = *(const bf16x8*)(Bs + (brow + 32 + l31) * 64 + ((ks * 2 + hi) ^ kx) * 8);
        if (t + 1 < 16) STAGE(d ^ 1, 0, 1, (t + 1) * 64);
        __builtin_amdgcn_s_barrier();
        __builtin_amdgcn_s_setprio(1);
#pragma unroll
        for (int ks = 0; ks < 4; ++ks) {
            acc[0][1] = MFMA32(af[0][ks], bf1[ks], acc[0][1]);
            acc[1][1] = MFMA32(af[1][ks], bf1[ks], acc[1][1]);
        }
        __builtin_amdgcn_s_setprio(0);
        __builtin_amdgcn_s_barrier();

        // ---- P3: read A(fm2,3); stage B-h0(t+2); MFMA C[2][1],C[3][1]
#pragma unroll
        for (int mf = 0; mf < 2; ++mf)
#pragma unroll
            for (int ks = 0; ks < 4; ++ks)
                af[mf][ks] = *(const bf16x8*)(As + ((2 + mf) * 32 + l31) * 64 + ((ks * 2 + hi) ^ kx) * 8);
        if (t + 2 < 16) STAGE(d, 1, 0, (t + 2) * 64);
        __builtin_amdgcn_s_barrier();
        __builtin_amdgcn_s_setprio(1);
#pragma unroll
        for (int ks = 0; ks < 4; ++ks) {
            acc[2][1] = MFMA32(af[0][ks], bf1[ks], acc[2][1]);
            acc[3][1] = MFMA32(af[1][ks], bf1[ks], acc[3][1]);
        }
        __builtin_amdgcn_s_setprio(0);
        __builtin_amdgcn_s_barrier();

        // ---- P4: stage A-h0(t+2); MFMA C[2][0],C[3][0]; counted vmcnt
        if (t + 2 < 16) STAGE(d, 0, 0, (t + 2) * 64);
        __builtin_amdgcn_s_barrier();
        __builtin_amdgcn_s_setprio(1);
#pragma unroll
        for (int ks = 0; ks < 4; ++ks) {
            acc[2][0] = MFMA32(af[0][ks], bf0[ks], acc[2][0]);
            acc[3][0] = MFMA32(af[1][ks], bf0[ks], acc[3][0]);
        }
        __builtin_amdgcn_s_setprio(0);
        if (t < 14) {
            asm volatile("s_waitcnt vmcnt(4)" ::: "memory");
        } else {
            asm volatile("s_waitcnt vmcnt(0)" ::: "memory");
        }
        __builtin_amdgcn_sched_barrier(0);
        __builtin_amdgcn_s_barrier();
    }

    // Epilogue. C 32x32 layout: col=l31, row=(r&3)+8*(r>>2)+4*hi.
#pragma unroll
    for (int fn = 0; fn < 2; ++fn) {
        const int cg = n0 + wn * 64 + fn * 32;   // frag col group (32 cols)
        const int cm = cg % 192;                 // 0,32=q 64,96=k 128,160=v
        const float bv = bias[cg + l31];
        if (cm >= 128) {
            // v-chunk -> Vt[b][h][d][s], bf16x4 along s
            const int hh = cg / 192;
            const int dd = cm - 128 + l31;
            const int bb = m0 >> 11;
            const int sb = (m0 + wm * 128) & 2047;
            __bf16* vt = Vt + ((size_t)(bb * Hq + hh) * HDq + dd) * Sq + sb;
#pragma unroll
            for (int fm = 0; fm < 4; ++fm)
#pragma unroll
                for (int g = 0; g < 4; ++g) {
                    bf16x4 vv;
#pragma unroll
                    for (int i = 0; i < 4; ++i) vv[i] = (__bf16)(acc[fm][fn][g * 4 + i] + bv);
                    *(bf16x4*)(vt + fm * 32 + g * 8 + hi * 4) = vv;
                }
        } else {
            const float sc = (cm < 64) ? QSCALE : 1.0f;
#pragma unroll
            for (int fm = 0; fm < 4; ++fm)
#pragma unroll
                for (int r = 0; r < 16; ++r) {
                    int m = m0 + wm * 128 + fm * 32 + (r & 3) + 8 * (r >> 2) + 4 * hi;
                    qkvb[(size_t)m * QKV_N + cg + l31] = (__bf16)((acc[fm][fn][r] + bv) * sc);
                }
        }
    }
}

// ---------------------------------------------------------------------------
// C[M,N] = A[M,K] @ BT[N,K]^T + bias[N]  (m97-ladder structure, f32 out).
__global__ __launch_bounds__(256) void gemm_out_kernel(const __bf16* __restrict__ A,
                                                       const __bf16* __restrict__ BT,
                                                       const float* __restrict__ bias,
                                                       float* __restrict__ Cout,
                                                       int M, int N, int K) {
    __shared__ __bf16 As[128 * 32];
    __shared__ __bf16 Bs[128 * 32];

    const int t = threadIdx.x;
    const int lane = t & 63;
    const int wave = t >> 6;
    const int wm = wave & 1, wn = wave >> 1;
    const int l15 = lane & 15;
    const int kg = (lane >> 4) * 8;

    const int m0 = blockIdx.y * 128;
    const int n0 = blockIdx.x * 128;

    const int srow = t >> 2;
    const int scol = (t & 3) * 8;
    const __bf16* ag = A  + (size_t)(m0 + srow) * K + scol;
    const __bf16* bg = BT + (size_t)(n0 + srow) * K + scol;
    __bf16* al = As + t * 8;
    __bf16* bl = Bs + t * 8;

    floatx4 acc[4][4] = {};

    for (int k0 = 0; k0 < K; k0 += 32) {
        __syncthreads();
        async16(ag + k0,                    al);
        async16(ag + (size_t)64 * K + k0,   al + 2048);
        async16(bg + k0,                    bl);
        async16(bg + (size_t)64 * K + k0,   bl + 2048);
        __syncthreads();

        bf16x8 af[4], bfr[4];
#pragma unroll
        for (int mi = 0; mi < 4; ++mi)
            af[mi] = *(const bf16x8*)(As + (wm * 64 + mi * 16 + l15) * 32 + kg);
#pragma unroll
        for (int ni = 0; ni < 4; ++ni)
            bfr[ni] = *(const bf16x8*)(Bs + (wn * 64 + ni * 16 + l15) * 32 + kg);
#pragma unroll
        for (int mi = 0; mi < 4; ++mi)
#pragma unroll
            for (int ni = 0; ni < 4; ++ni)
                acc[mi][ni] = MFMA16(af[mi], bfr[ni], acc[mi][ni]);
    }

    // C/D layout: col = lane&15, row = (lane>>4)*4 + reg   [verified m89/m91]
    const int r0 = (lane >> 4) * 4;
    const int wn0 = n0 + wn * 64;

#pragma unroll
    for (int ni = 0; ni < 4; ++ni) {
        int col = wn0 + ni * 16 + l15;
        float bv = bias[col];
#pragma unroll
        for (int mi = 0; mi < 4; ++mi) {
#pragma unroll
            for (int i = 0; i < 4; ++i) {
                int row = m0 + wm * 64 + mi * 16 + r0 + i;
                Cout[(size_t)row * N + col] = acc[mi][ni][i] + bv;
            }
        }
    }
}

// ---------------------------------------------------------------------------
// Flash attention, 32x32-MFMA transposed compute (S^T = K Q^T, O^T = V^T P^T),
// max-free softmax (q pre-scaled by 0.125*log2e -> p = exp2(s)).
//
// R5: split-K reverted (R4: __launch_bounds__(256,4) capped regs at 128 ->
// accumulator spill -> 2.2 GB scratch traffic. This kernel NEEDS ~220 regs:
// occupancy is 2 waves/SIMD by register pressure, grid-limited anyway).
// Instead: ILP restructure at fixed occupancy -- both key-halves' QK^T
// computed first (4 independent MFMA chains), then sm(h0) -> PV(h0) ->
// sm(h1) (overlaps PV(h0) in the MFMA pipe) -> PV(h1). T5 setprio around
// MFMA clusters (+4-7% attn, m191).
//
// Wave owns 64 q rows; block = one (b,h) x 256 q rows; grid bh-major
// (gridDim.x=64, 0 mod 8) -> K/V L2 residency per XCD (T1).
__global__ __launch_bounds__(256, 2) void attn_kernel(const __bf16* __restrict__ qkv,
                                                      const __bf16* __restrict__ Vt,
                                                      __bf16* __restrict__ v2) {
    const int bh = blockIdx.x;
    const int b = bh >> 4, h = bh & 15;
    const int q0 = blockIdx.y * 256;
    const int tid  = threadIdx.x;
    const int lane = tid & 63;
    const int wave = tid >> 6;
    const int l31  = lane & 31;
    const int hi   = lane >> 5;          // half-wave index
    const int kx   = l31 & 7;            // row XOR key for LDS swizzle
    const size_t rs = QKV_N;
    const __bf16* base  = qkv + (size_t)b * Sq * rs + (size_t)h * (3 * HDq);
    const __bf16* vbase = Vt + (size_t)bh * HDq * Sq;

    __shared__ alignas(16) __bf16 Ks[2][64][64];   // [buf][key][d]   (swizzled)
    __shared__ alignas(16) __bf16 Vs[2][64][64];   // [buf][d][key]   (swizzled)

    // Q B-frags, two 32-q groups: lane holds Q[q][d = hi*8 + j + st*16]
    bf16x8 qb[2][4];
#pragma unroll
    for (int qg = 0; qg < 2; ++qg) {
        const __bf16* qr = base + (size_t)(q0 + wave * 64 + qg * 32 + l31) * rs + hi * 8;
#pragma unroll
        for (int st = 0; st < 4; ++st) qb[qg][st] = *(const bf16x8*)(qr + st * 16);
    }

    // Staging map: wave-issue covers 8 rows x 64 cols (1 KiB); lane ->
    // (row = base+lane/8, slot = lane&7). LDS dest is linear (base+lane*16);
    // the XOR swizzle lives in the GLOBAL source slot: slot ^ (row&7).
    const int rA = wave * 8 + (lane >> 3);          // rows 0..31
    const int rB = rA + 32;                         // rows 32..63 (same &7)
    const int sw = ((lane & 7) ^ (rA & 7)) * 8;     // pre-swizzled elem offset
    const __bf16* gK0 = base + HDq + (size_t)rA * rs + sw;
    const __bf16* gK1 = base + HDq + (size_t)rB * rs + sw;
    const __bf16* gV0 = vbase + (size_t)rA * Sq + sw;
    const __bf16* gV1 = vbase + (size_t)rB * Sq + sw;
    const int loff0 = wave * 512 + lane * 8;        // elem offsets into a buf
    const int loff1 = (4 + wave) * 512 + lane * 8;

    auto STAGE = [&](int bufi, int kt) {
        const size_t ko = (size_t)kt * rs;
        async16(gK0 + ko, &Ks[bufi][0][0] + loff0);
        async16(gK1 + ko, &Ks[bufi][0][0] + loff1);
        async16(gV0 + kt, &Vs[bufi][0][0] + loff0);
        async16(gV1 + kt, &Vs[bufi][0][0] + loff1);
    };

    // exp2 + bf16 pack + permlane regroup: c (16 scores) -> 2 PV B-frags.
    auto softmax_pb = [&](const floatx16& c, float& la, bf16x8* pb) {
        unsigned int W[8];
        float s0 = 0.f, s1 = 0.f;
#pragma unroll
        for (int m = 0; m < 8; ++m) {
            float e0 = __builtin_amdgcn_exp2f(c[2 * m]);
            float e1 = __builtin_amdgcn_exp2f(c[2 * m + 1]);
            s0 += e0; s1 += e1;              // two independent add chains
            union { bf16x2 v; unsigned int u; } pk;
            pk.v[0] = (__bf16)e0; pk.v[1] = (__bf16)e1;
            W[m] = pk.u;
        }
        la += s0 + s1;
#pragma unroll
        for (int ks = 0; ks < 2; ++ks) {
            auto r0 = __builtin_amdgcn_permlane32_swap(W[ks * 4 + 0], W[ks * 4 + 2], false, false);
            auto r1 = __builtin_amdgcn_permlane32_swap(W[ks * 4 + 1], W[ks * 4 + 3], false, false);
            uintx4 bb; bb[0] = r0[0]; bb[1] = r1[0]; bb[2] = r0[1]; bb[3] = r1[1];
            pb[ks] = __builtin_bit_cast(bf16x8, bb);
        }
    };

    floatx16 o[2][2] = {};   // [qg][d-half]: O^T d rows 0..31 / 32..63, col q
    float la0 = 0.f, la1 = 0.f;

    STAGE(0, 0);
    __syncthreads();             // compiler drains vmcnt before s_barrier

    int cur = 0;
    for (int kt = 0; kt < Sq; kt += 64, cur ^= 1) {
        if (kt + 64 < Sq) STAGE(cur ^ 1, kt + 64);  // in flight across compute

        // --- QK^T, BOTH halves: 16 MFMAs in 4 independent chains.
        bf16x8 ka0[4], ka1[4];
#pragma unroll
        for (int st = 0; st < 4; ++st) {
            ka0[st] = *(const bf16x8*)(&Ks[cur][l31][((st * 2 + hi) ^ kx) * 8]);
            ka1[st] = *(const bf16x8*)(&Ks[cur][32 + l31][((st * 2 + hi) ^ kx) * 8]);
        }
        floatx16 c00 = {}, c01 = {}, c10 = {}, c11 = {};
        __builtin_amdgcn_s_setprio(1);
#pragma unroll
        for (int st = 0; st < 4; ++st) {
            c00 = MFMA32(ka0[st], qb[0][st], c00);
            c10 = MFMA32(ka1[st], qb[0][st], c10);
            c01 = MFMA32(ka0[st], qb[1][st], c01);
            c11 = MFMA32(ka1[st], qb[1][st], c11);
        }
        __builtin_amdgcn_s_setprio(0);

        // --- sm(h0) -> PV(h0); sm(h1) overlaps PV(h0)'s MFMA occupancy.
        bf16x8 pb00[2], pb01[2], pb10[2], pb11[2];
        softmax_pb(c00, la0, pb00);
        softmax_pb(c01, la1, pb01);
        __builtin_amdgcn_s_setprio(1);
#pragma unroll
        for (int ks = 0; ks < 2; ++ks) {
            const int kslot = ks * 2 + hi;             // h0 key-slots 0..3
            bf16x8 va0 = *(const bf16x8*)(&Vs[cur][l31][(kslot ^ kx) * 8]);
            bf16x8 va1 = *(const bf16x8*)(&Vs[cur][32 + l31][(kslot ^ kx) * 8]);
            o[0][0] = MFMA32(va0, pb00[ks], o[0][0]);
            o[0][1] = MFMA32(va1, pb00[ks], o[0][1]);
            o[1][0] = MFMA32(va0, pb01[ks], o[1][0]);
            o[1][1] = MFMA32(va1, pb01[ks], o[1][1]);
        }
        __builtin_amdgcn_s_setprio(0);
        softmax_pb(c10, la0, pb10);
        softmax_pb(c11, la1, pb11);
        __builtin_amdgcn_s_setprio(1);
#pragma unroll
        for (int ks = 0; ks < 2; ++ks) {
            const int kslot = 4 + ks * 2 + hi;         // h1 key-slots 4..7
            bf16x8 va0 = *(const bf16x8*)(&Vs[cur][l31][(kslot ^ kx) * 8]);
            bf16x8 va1 = *(const bf16x8*)(&Vs[cur][32 + l31][(kslot ^ kx) * 8]);
            o[0][0] = MFMA32(va0, pb10[ks], o[0][0]);
            o[0][1] = MFMA32(va1, pb10[ks], o[0][1]);
            o[1][0] = MFMA32(va0, pb11[ks], o[1][0]);
            o[1][1] = MFMA32(va1, pb11[ks], o[1][1]);
        }
        __builtin_amdgcn_s_setprio(0);

        __syncthreads();  // drains stage vmcnt; protects buf reuse
    }

    // l reduction: lanes l and l^32 hold the two key-halves of the same q.
    // Epilogue per q-group. O^T C-layout: col q=l31, row d=(reg&3)+8*(reg>>2)+4*hi.
    // Quirk reshape: v2[b*2048 + h*128 + q/16][(q%16)*64 + d]
#pragma unroll
    for (int qg = 0; qg < 2; ++qg) {
        float lsum = qg ? la1 : la0;
        float l = lsum + __shfl_xor(lsum, 32);
        float rinv = 1.0f / l;
        const int q = q0 + wave * 64 + qg * 32 + l31;
        size_t row = (size_t)b * Sq + h * 128 + (q >> 4);
        __bf16* vrow = v2 + row * Dq + (size_t)(q & 15) * 64;
#pragma unroll
        for (int gg = 0; gg < 4; ++gg) {
            bf16x4 ov;
#pragma unroll
            for (int i = 0; i < 4; ++i) ov[i] = (__bf16)(o[qg][0][gg * 4 + i] * rinv);
            *(bf16x4*)(vrow + gg * 8 + hi * 4) = ov;
#pragma unroll
            for (int i = 0; i < 4; ++i) ov[i] = (__bf16)(o[qg][1][gg * 4 + i] * rinv);
            *(bf16x4*)(vrow + 32 + gg * 8 + hi * 4) = ov;
        }
    }
}

// ---------------------------------------------------------------------------
extern "C" void kernel_launch(void* const* d_in, const int* in_sizes, int n_in,
                              void* d_out, int out_size, void* d_ws, size_t ws_size,
                              hipStream_t stream) {
    const float* x    = (const float*)d_in[0];  // [4,2048,1024]
    const float* Wqkv = (const float*)d_in[1];  // [1024,3072]
    const float* bqkv = (const float*)d_in[2];  // [3072]
    const float* Wo   = (const float*)d_in[3];  // [1024,1024]
    const float* bo   = (const float*)d_in[4];  // [1024]
    float* out = (float*)d_out;                 // [4,2048,1024] f32

    __bf16* xb    = (__bf16*)d_ws;                        // 8192*1024
    __bf16* WqkvT = xb    + (size_t)ROWS * Dq;            // 3072*1024
    __bf16* WoT   = WqkvT + (size_t)QKV_N * Dq;           // 1024*1024
    __bf16* qkvb  = WoT   + (size_t)Dq * Dq;              // 8192*3072
    __bf16* Vt    = qkvb  + (size_t)ROWS * QKV_N;         // 64*64*2048
    __bf16* v2    = xb;                                   // alias (xb dead)

    prep_kernel<<<12288, 256, 0, stream>>>((const float4*)x, (bf16x4*)xb,
                                           Wqkv, WqkvT, Wo, WoT);

    gemm_qkv_kernel<<<dim3(QKV_N / 256, ROWS / 256), 512, 0, stream>>>(
        xb, WqkvT, bqkv, qkvb, Vt);

    attn_kernel<<<dim3(Bq * Hq, Sq / 256), 256, 0, stream>>>(qkvb, Vt, v2);

    gemm_out_kernel<<<dim3(Dq / 128, ROWS / 128), 256, 0, stream>>>(
        v2, WoT, bo, out, ROWS, Dq, Dq);
}

// Round 6
// 267.537 us; speedup vs baseline: 2.6522x; 1.0076x over previous
//
#include <hip/hip_runtime.h>
#include <hip/hip_bf16.h>
#include <cstdint>

// Problem constants: B=4, S=2048, D=1024, H=16, HD=64
static constexpr int Bq  = 4;
static constexpr int Sq  = 2048;
static constexpr int Dq  = 1024;
static constexpr int Hq  = 16;
static constexpr int HDq = 64;
static constexpr int ROWS = Bq * Sq;        // 8192
static constexpr int QKV_N = 3 * Dq;        // 3072

typedef __bf16 bf16x8 __attribute__((ext_vector_type(8)));
typedef __bf16 bf16x4 __attribute__((ext_vector_type(4)));
typedef __bf16 bf16x2 __attribute__((ext_vector_type(2)));
typedef float  floatx4 __attribute__((ext_vector_type(4)));
typedef float  floatx16 __attribute__((ext_vector_type(16)));
typedef unsigned int uintx4 __attribute__((ext_vector_type(4)));

#define MFMA16(a, b, c) __builtin_amdgcn_mfma_f32_16x16x32_bf16((a), (b), (c), 0, 0, 0)
#define MFMA32(a, b, c) __builtin_amdgcn_mfma_f32_32x32x16_bf16((a), (b), (c), 0, 0, 0)

// 0.125 (1/sqrt(HD)) * log2(e): folded into q so softmax uses exp2 directly.
#define QSCALE 0.18033688011112042f

// Async global->LDS 16B copy (global_load_lds_dwordx4).
__device__ __forceinline__ void async16(const void* g, void* l) {
    __builtin_amdgcn_global_load_lds(
        (const __attribute__((address_space(1))) uint32_t*)g,
        (__attribute__((address_space(3))) uint32_t*)l, 16, 0, 0);
}

// ---------------------------------------------------------------------------
// Fused prep: fp32->bf16 convert of x (blocks [0,8192)), Wqkv transpose-cvt
// (blocks [8192,11264)), Wo transpose-cvt (blocks [11264,12288)).
__global__ __launch_bounds__(256) void prep_kernel(const float4* __restrict__ x4,
                                                   bf16x4* __restrict__ xb4,
                                                   const float* __restrict__ Wqkv,
                                                   __bf16* __restrict__ WqkvT,
                                                   const float* __restrict__ Wo,
                                                   __bf16* __restrict__ WoT) {
    __shared__ float t[32][33];
    const int bx = blockIdx.x;
    if (bx < 8192) {
        int i = bx * 256 + threadIdx.x;      // 8192*256 == ROWS*Dq/4 exactly
        float4 v = x4[i];
        bf16x4 o;
        o[0] = (__bf16)v.x; o[1] = (__bf16)v.y; o[2] = (__bf16)v.z; o[3] = (__bf16)v.w;
        xb4[i] = o;
        return;
    }
    const float* in; __bf16* out; int K, N, bid;
    if (bx < 8192 + 3072) { bid = bx - 8192;  in = Wqkv; out = WqkvT; K = Dq; N = QKV_N; }
    else                  { bid = bx - 11264; in = Wo;   out = WoT;   K = Dq; N = Dq; }
    const int nt = N / 32;
    const int n0 = (bid % nt) * 32, k0 = (bid / nt) * 32;
    const int c = threadIdx.x & 31, r0 = threadIdx.x >> 5;
#pragma unroll
    for (int rr = 0; rr < 32; rr += 8)
        t[r0 + rr][c] = in[(size_t)(k0 + r0 + rr) * N + n0 + c];
    __syncthreads();
#pragma unroll
    for (int rr = 0; rr < 32; rr += 8)
        out[(size_t)(n0 + r0 + rr) * K + k0 + c] = (__bf16)t[c][r0 + rr];
}

// ---------------------------------------------------------------------------
// QKV GEMM: qkv[8192,3072] = xb[8192,1024] @ WqkvT[3072,1024]^T + bqkv.
//
// R6 retile: 256x192 tile (was 256x256). Grid 16x32 = 512 blocks = EXACTLY
// 2 rounds at 1 block/CU -> 100% round-quantization (R5 counters: 384-block
// grid ran at 644 TF = 0.76 x m248's 848 TF reference, the exact 384/512
// quantization loss). 192 cols = one (q,k,v) head-triple -> wave-static
// epilogue classification.
//
// 8 waves as 4M x 2N: wave owns 64 rows x 96 cols = 2x3 frags of 32x32
// (acc = 96 VGPR). BK=64; LDS = 2 bufs x 7 units x [64][64] bf16 = 112 KiB.
// Unit u: 0-3 = A rows u*64..+63; 4-6 = B rows (u-4)*64..+63. One async16
// per thread per unit (512 thr x 16 B = 8 KB), XOR-swizzled global source +
// swizzled ds_read_b128 (rule 21).
//
// 3 phases per K-tile t (T3+T4+T5): P1 {read A-frags + B-fn0; stage 3 B
// units of t+1} P2 {read B-fn1; stage A units 0,1 of t+2} P3 {read B-fn2;
// stage A units 2,3 of t+2; vmcnt(4)}. The counted vmcnt leaves exactly
// t+2's A units in flight and guarantees all 7 units of t+1 have landed.
// A-unit overwrite in P2/P3 is safe: A-frags are register-resident after
// P1, and P1's ds_reads complete before its MFMAs (lgkmcnt) hence before
// its closing barrier.
__global__ __launch_bounds__(512, 2) void gemm_qkv_kernel(const __bf16* __restrict__ A,
                                                          const __bf16* __restrict__ BT,
                                                          const float* __restrict__ bias,
                                                          __bf16* __restrict__ qkvb,
                                                          __bf16* __restrict__ Vt) {
    __shared__ __bf16 lds[2][7][64][64];   // 112 KiB

    const int tid  = threadIdx.x;
    const int lane = tid & 63;
    const int wave = tid >> 6;
    const int wm = wave >> 1;            // 0..3 : 64-row group
    const int wn = wave & 1;             // 0..1 : 96-col group
    const int l31 = lane & 31;
    const int hi  = lane >> 5;
    const int kx  = l31 & 7;             // row XOR key for LDS swizzle

    const int m0 = blockIdx.y * 256;
    const int n0 = blockIdx.x * 192;

    // Staging map (per unit): wave w covers rows w*8..+7; lane -> (row =
    // w*8 + l/8, dest slot = l&7). LDS dest linear (base + lane*16); swizzle
    // in the GLOBAL source slot: (l&7) ^ (row&7) with row&7 == l>>3.
    const int sw = ((lane & 7) ^ (lane >> 3)) * 8;    // swizzled elem offset
    const __bf16* gA = A  + (size_t)(m0 + wave * 8 + (lane >> 3)) * 1024 + sw;
    const __bf16* gB = BT + (size_t)(n0 + wave * 8 + (lane >> 3)) * 1024 + sw;

    auto STAGEA = [&](int buf, int u, int ktel) {
        async16(gA + (size_t)u * 65536 + ktel, &lds[buf][u][0][0] + wave * 512 + lane * 8);
    };
    auto STAGEB = [&](int buf, int j, int ktel) {
        async16(gB + (size_t)j * 65536 + ktel, &lds[buf][4 + j][0][0] + wave * 512 + lane * 8);
    };

    floatx16 acc[2][3] = {};   // [fm][fn] 32x32 frags

    // Prologue: tile0 fully (A units then B units) + A units of tile1.
#pragma unroll
    for (int u = 0; u < 4; ++u) STAGEA(0, u, 0);
#pragma unroll
    for (int j = 0; j < 3; ++j) STAGEB(0, j, 0);
#pragma unroll
    for (int u = 0; u < 4; ++u) STAGEA(1, u, 64);
    asm volatile("s_waitcnt vmcnt(4)" ::: "memory");  // tile0's 7 units landed
    __builtin_amdgcn_sched_barrier(0);
    __builtin_amdgcn_s_barrier();

    bf16x8 af[2][4], bf[4];

    for (int t = 0; t < 16; ++t) {
        const int d = t & 1;

        // ---- P1: read A(fm0,1) + B(fn0); stage B units of t+1; MFMA col 0
#pragma unroll
        for (int fm = 0; fm < 2; ++fm)
#pragma unroll
            for (int ks = 0; ks < 4; ++ks)
                af[fm][ks] = *(const bf16x8*)(&lds[d][wm][fm * 32 + l31][((ks * 2 + hi) ^ kx) * 8]);
        {
            const int br = wn * 96;
#pragma unroll
            for (int ks = 0; ks < 4; ++ks)
                bf[ks] = *(const bf16x8*)(&lds[d][4 + (br >> 6)][(br & 63) + l31][((ks * 2 + hi) ^ kx) * 8]);
        }
        if (t + 1 < 16) {
            STAGEB(d ^ 1, 0, (t + 1) * 64);
            STAGEB(d ^ 1, 1, (t + 1) * 64);
            STAGEB(d ^ 1, 2, (t + 1) * 64);
        }
        __builtin_amdgcn_s_barrier();
        __builtin_amdgcn_s_setprio(1);
#pragma unroll
        for (int ks = 0; ks < 4; ++ks) {
            acc[0][0] = MFMA32(af[0][ks], bf[ks], acc[0][0]);
            acc[1][0] = MFMA32(af[1][ks], bf[ks], acc[1][0]);
        }
        __builtin_amdgcn_s_setprio(0);
        __builtin_amdgcn_s_barrier();

        // ---- P2: read B(fn1); stage A units 0,1 of t+2; MFMA col 1
        {
            const int br = wn * 96 + 32;
#pragma unroll
            for (int ks = 0; ks < 4; ++ks)
                bf[ks] = *(const bf16x8*)(&lds[d][4 + (br >> 6)][(br & 63) + l31][((ks * 2 + hi) ^ kx) * 8]);
        }
        if (t + 2 < 16) {
            STAGEA(d, 0, (t + 2) * 64);
            STAGEA(d, 1, (t + 2) * 64);
        }
        __builtin_amdgcn_s_barrier();
        __builtin_amdgcn_s_setprio(1);
#pragma unroll
        for (int ks = 0; ks < 4; ++ks) {
            acc[0][1] = MFMA32(af[0][ks], bf[ks], acc[0][1]);
            acc[1][1] = MFMA32(af[1][ks], bf[ks], acc[1][1]);
        }
        __builtin_amdgcn_s_setprio(0);
        __builtin_amdgcn_s_barrier();

        // ---- P3: read B(fn2); stage A units 2,3 of t+2; MFMA col 2; vmcnt
        {
            const int br = wn * 96 + 64;
#pragma unroll
            for (int ks = 0; ks < 4; ++ks)
                bf[ks] = *(const bf16x8*)(&lds[d][4 + (br >> 6)][(br & 63) + l31][((ks * 2 + hi) ^ kx) * 8]);
        }
        if (t + 2 < 16) {
            STAGEA(d, 2, (t + 2) * 64);
            STAGEA(d, 3, (t + 2) * 64);
        }
        __builtin_amdgcn_s_barrier();
        __builtin_amdgcn_s_setprio(1);
#pragma unroll
        for (int ks = 0; ks < 4; ++ks) {
            acc[0][2] = MFMA32(af[0][ks], bf[ks], acc[0][2]);
            acc[1][2] = MFMA32(af[1][ks], bf[ks], acc[1][2]);
        }
        __builtin_amdgcn_s_setprio(0);
        if (t < 14) {
            asm volatile("s_waitcnt vmcnt(4)" ::: "memory");
        } else {
            asm volatile("s_waitcnt vmcnt(0)" ::: "memory");
        }
        __builtin_amdgcn_sched_barrier(0);
        __builtin_amdgcn_s_barrier();
    }

    // Epilogue. C 32x32 layout: col=l31, row=(r&3)+8*(r>>2)+4*hi.
    // cm = cg%192 is wave-static: wn=0 -> {0,32,64} (q,q,k);
    // wn=1 -> {96,128,160} (k,v,v).
#pragma unroll
    for (int fn = 0; fn < 3; ++fn) {
        const int cm = wn * 96 + fn * 32;        // cg % 192
        const int cg = n0 + cm;                  // frag col group (32 cols)
        const float bv = bias[cg + l31];
        if (cm >= 128) {
            // v-chunk -> Vt[b][h][d][s], bf16x4 along s
            const int hh = n0 / 192;             // = blockIdx.x
            const int dd = cm - 128 + l31;
            const int bb = m0 >> 11;
            const int sb = (m0 & 2047) + wm * 64;
            __bf16* vt = Vt + ((size_t)(bb * Hq + hh) * HDq + dd) * Sq + sb;
#pragma unroll
            for (int fm = 0; fm < 2; ++fm)
#pragma unroll
                for (int g = 0; g < 4; ++g) {
                    bf16x4 vv;
#pragma unroll
                    for (int i = 0; i < 4; ++i) vv[i] = (__bf16)(acc[fm][fn][g * 4 + i] + bv);
                    *(bf16x4*)(vt + fm * 32 + g * 8 + hi * 4) = vv;
                }
        } else {
            const float sc = (cm < 64) ? QSCALE : 1.0f;
#pragma unroll
            for (int fm = 0; fm < 2; ++fm)
#pragma unroll
                for (int r = 0; r < 16; ++r) {
                    int m = m0 + wm * 64 + fm * 32 + (r & 3) + 8 * (r >> 2) + 4 * hi;
                    qkvb[(size_t)m * QKV_N + cg + l31] = (__bf16)((acc[fm][fn][r] + bv) * sc);
                }
        }
    }
}

// ---------------------------------------------------------------------------
// C[M,N] = A[M,K] @ BT[N,K]^T + bias[N]  (m97-ladder structure, f32 out).
__global__ __launch_bounds__(256) void gemm_out_kernel(const __bf16* __restrict__ A,
                                                       const __bf16* __restrict__ BT,
                                                       const float* __restrict__ bias,
                                                       float* __restrict__ Cout,
                                                       int M, int N, int K) {
    __shared__ __bf16 As[128 * 32];
    __shared__ __bf16 Bs[128 * 32];

    const int t = threadIdx.x;
    const int lane = t & 63;
    const int wave = t >> 6;
    const int wm = wave & 1, wn = wave >> 1;
    const int l15 = lane & 15;
    const int kg = (lane >> 4) * 8;

    const int m0 = blockIdx.y * 128;
    const int n0 = blockIdx.x * 128;

    const int srow = t >> 2;
    const int scol = (t & 3) * 8;
    const __bf16* ag = A  + (size_t)(m0 + srow) * K + scol;
    const __bf16* bg = BT + (size_t)(n0 + srow) * K + scol;
    __bf16* al = As + t * 8;
    __bf16* bl = Bs + t * 8;

    floatx4 acc[4][4] = {};

    for (int k0 = 0; k0 < K; k0 += 32) {
        __syncthreads();
        async16(ag + k0,                    al);
        async16(ag + (size_t)64 * K + k0,   al + 2048);
        async16(bg + k0,                    bl);
        async16(bg + (size_t)64 * K + k0,   bl + 2048);
        __syncthreads();

        bf16x8 af[4], bfr[4];
#pragma unroll
        for (int mi = 0; mi < 4; ++mi)
            af[mi] = *(const bf16x8*)(As + (wm * 64 + mi * 16 + l15) * 32 + kg);
#pragma unroll
        for (int ni = 0; ni < 4; ++ni)
            bfr[ni] = *(const bf16x8*)(Bs + (wn * 64 + ni * 16 + l15) * 32 + kg);
#pragma unroll
        for (int mi = 0; mi < 4; ++mi)
#pragma unroll
            for (int ni = 0; ni < 4; ++ni)
                acc[mi][ni] = MFMA16(af[mi], bfr[ni], acc[mi][ni]);
    }

    // C/D layout: col = lane&15, row = (lane>>4)*4 + reg   [verified m89/m91]
    const int r0 = (lane >> 4) * 4;
    const int wn0 = n0 + wn * 64;

#pragma unroll
    for (int ni = 0; ni < 4; ++ni) {
        int col = wn0 + ni * 16 + l15;
        float bv = bias[col];
#pragma unroll
        for (int mi = 0; mi < 4; ++mi) {
#pragma unroll
            for (int i = 0; i < 4; ++i) {
                int row = m0 + wm * 64 + mi * 16 + r0 + i;
                Cout[(size_t)row * N + col] = acc[mi][ni][i] + bv;
            }
        }
    }
}

// ---------------------------------------------------------------------------
// Flash attention, 32x32-MFMA transposed compute (S^T = K Q^T, O^T = V^T P^T),
// max-free softmax (q pre-scaled by 0.125*log2e -> p = exp2(s)).
// ILP structure (R5): both key-halves' QK^T first (4 independent MFMA
// chains), then sm(h0) -> PV(h0) -> sm(h1) (overlaps PV(h0)) -> PV(h1).
// T5 setprio around MFMA clusters. 2 waves/SIMD by register pressure --
// do NOT raise the launch-bounds occupancy arg (R4: acc spill, 2.2 GB
// scratch traffic).
__global__ __launch_bounds__(256, 2) void attn_kernel(const __bf16* __restrict__ qkv,
                                                      const __bf16* __restrict__ Vt,
                                                      __bf16* __restrict__ v2) {
    const int bh = blockIdx.x;
    const int b = bh >> 4, h = bh & 15;
    const int q0 = blockIdx.y * 256;
    const int tid  = threadIdx.x;
    const int lane = tid & 63;
    const int wave = tid >> 6;
    const int l31  = lane & 31;
    const int hi   = lane >> 5;          // half-wave index
    const int kx   = l31 & 7;            // row XOR key for LDS swizzle
    const size_t rs = QKV_N;
    const __bf16* base  = qkv + (size_t)b * Sq * rs + (size_t)h * (3 * HDq);
    const __bf16* vbase = Vt + (size_t)bh * HDq * Sq;

    __shared__ alignas(16) __bf16 Ks[2][64][64];   // [buf][key][d]   (swizzled)
    __shared__ alignas(16) __bf16 Vs[2][64][64];   // [buf][d][key]   (swizzled)

    // Q B-frags, two 32-q groups: lane holds Q[q][d = hi*8 + j + st*16]
    bf16x8 qb[2][4];
#pragma unroll
    for (int qg = 0; qg < 2; ++qg) {
        const __bf16* qr = base + (size_t)(q0 + wave * 64 + qg * 32 + l31) * rs + hi * 8;
#pragma unroll
        for (int st = 0; st < 4; ++st) qb[qg][st] = *(const bf16x8*)(qr + st * 16);
    }

    // Staging map: wave-issue covers 8 rows x 64 cols (1 KiB); lane ->
    // (row = base+lane/8, slot = lane&7). LDS dest is linear (base+lane*16);
    // the XOR swizzle lives in the GLOBAL source slot: slot ^ (row&7).
    const int rA = wave * 8 + (lane >> 3);          // rows 0..31
    const int rB = rA + 32;                         // rows 32..63 (same &7)
    const int sw = ((lane & 7) ^ (rA & 7)) * 8;     // pre-swizzled elem offset
    const __bf16* gK0 = base + HDq + (size_t)rA * rs + sw;
    const __bf16* gK1 = base + HDq + (size_t)rB * rs + sw;
    const __bf16* gV0 = vbase + (size_t)rA * Sq + sw;
    const __bf16* gV1 = vbase + (size_t)rB * Sq + sw;
    const int loff0 = wave * 512 + lane * 8;        // elem offsets into a buf
    const int loff1 = (4 + wave) * 512 + lane * 8;

    auto STAGE = [&](int bufi, int kt) {
        const size_t ko = (size_t)kt * rs;
        async16(gK0 + ko, &Ks[bufi][0][0] + loff0);
        async16(gK1 + ko, &Ks[bufi][0][0] + loff1);
        async16(gV0 + kt, &Vs[bufi][0][0] + loff0);
        async16(gV1 + kt, &Vs[bufi][0][0] + loff1);
    };

    // exp2 + bf16 pack + permlane regroup: c (16 scores) -> 2 PV B-frags.
    auto softmax_pb = [&](const floatx16& c, float& la, bf16x8* pb) {
        unsigned int W[8];
        float s0 = 0.f, s1 = 0.f;
#pragma unroll
        for (int m = 0; m < 8; ++m) {
            float e0 = __builtin_amdgcn_exp2f(c[2 * m]);
            float e1 = __builtin_amdgcn_exp2f(c[2 * m + 1]);
            s0 += e0; s1 += e1;              // two independent add chains
            union { bf16x2 v; unsigned int u; } pk;
            pk.v[0] = (__bf16)e0; pk.v[1] = (__bf16)e1;
            W[m] = pk.u;
        }
        la += s0 + s1;
#pragma unroll
        for (int ks = 0; ks < 2; ++ks) {
            auto r0 = __builtin_amdgcn_permlane32_swap(W[ks * 4 + 0], W[ks * 4 + 2], false, false);
            auto r1 = __builtin_amdgcn_permlane32_swap(W[ks * 4 + 1], W[ks * 4 + 3], false, false);
            uintx4 bb; bb[0] = r0[0]; bb[1] = r1[0]; bb[2] = r0[1]; bb[3] = r1[1];
            pb[ks] = __builtin_bit_cast(bf16x8, bb);
        }
    };

    floatx16 o[2][2] = {};   // [qg][d-half]: O^T d rows 0..31 / 32..63, col q
    float la0 = 0.f, la1 = 0.f;

    STAGE(0, 0);
    __syncthreads();             // compiler drains vmcnt before s_barrier

    int cur = 0;
    for (int kt = 0; kt < Sq; kt += 64, cur ^= 1) {
        if (kt + 64 < Sq) STAGE(cur ^ 1, kt + 64);  // in flight across compute

        // --- QK^T, BOTH halves: 16 MFMAs in 4 independent chains.
        bf16x8 ka0[4], ka1[4];
#pragma unroll
        for (int st = 0; st < 4; ++st) {
            ka0[st] = *(const bf16x8*)(&Ks[cur][l31][((st * 2 + hi) ^ kx) * 8]);
            ka1[st] = *(const bf16x8*)(&Ks[cur][32 + l31][((st * 2 + hi) ^ kx) * 8]);
        }
        floatx16 c00 = {}, c01 = {}, c10 = {}, c11 = {};
        __builtin_amdgcn_s_setprio(1);
#pragma unroll
        for (int st = 0; st < 4; ++st) {
            c00 = MFMA32(ka0[st], qb[0][st], c00);
            c10 = MFMA32(ka1[st], qb[0][st], c10);
            c01 = MFMA32(ka0[st], qb[1][st], c01);
            c11 = MFMA32(ka1[st], qb[1][st], c11);
        }
        __builtin_amdgcn_s_setprio(0);

        // --- sm(h0) -> PV(h0); sm(h1) overlaps PV(h0)'s MFMA occupancy.
        bf16x8 pb00[2], pb01[2], pb10[2], pb11[2];
        softmax_pb(c00, la0, pb00);
        softmax_pb(c01, la1, pb01);
        __builtin_amdgcn_s_setprio(1);
#pragma unroll
        for (int ks = 0; ks < 2; ++ks) {
            const int kslot = ks * 2 + hi;             // h0 key-slots 0..3
            bf16x8 va0 = *(const bf16x8*)(&Vs[cur][l31][(kslot ^ kx) * 8]);
            bf16x8 va1 = *(const bf16x8*)(&Vs[cur][32 + l31][(kslot ^ kx) * 8]);
            o[0][0] = MFMA32(va0, pb00[ks], o[0][0]);
            o[0][1] = MFMA32(va1, pb00[ks], o[0][1]);
            o[1][0] = MFMA32(va0, pb01[ks], o[1][0]);
            o[1][1] = MFMA32(va1, pb01[ks], o[1][1]);
        }
        __builtin_amdgcn_s_setprio(0);
        softmax_pb(c10, la0, pb10);
        softmax_pb(c11, la1, pb11);
        __builtin_amdgcn_s_setprio(1);
#pragma unroll
        for (int ks = 0; ks < 2; ++ks) {
            const int kslot = 4 + ks * 2 + hi;         // h1 key-slots 4..7
            bf16x8 va0 = *(const bf16x8*)(&Vs[cur][l31][(kslot ^ kx) * 8]);
            bf16x8 va1 = *(const bf16x8*)(&Vs[cur][32 + l31][(kslot ^ kx) * 8]);
            o[0][0] = MFMA32(va0, pb10[ks], o[0][0]);
            o[0][1] = MFMA32(va1, pb10[ks], o[0][1]);
            o[1][0] = MFMA32(va0, pb11[ks], o[1][0]);
            o[1][1] = MFMA32(va1, pb11[ks], o[1][1]);
        }
        __builtin_amdgcn_s_setprio(0);

        __syncthreads();  // drains stage vmcnt; protects buf reuse
    }

    // l reduction: lanes l and l^32 hold the two key-halves of the same q.
    // Epilogue per q-group. O^T C-layout: col q=l31, row d=(reg&3)+8*(reg>>2)+4*hi.
    // Quirk reshape: v2[b*2048 + h*128 + q/16][(q%16)*64 + d]
#pragma unroll
    for (int qg = 0; qg < 2; ++qg) {
        float lsum = qg ? la1 : la0;
        float l = lsum + __shfl_xor(lsum, 32);
        float rinv = 1.0f / l;
        const int q = q0 + wave * 64 + qg * 32 + l31;
        size_t row = (size_t)b * Sq + h * 128 + (q >> 4);
        __bf16* vrow = v2 + row * Dq + (size_t)(q & 15) * 64;
#pragma unroll
        for (int gg = 0; gg < 4; ++gg) {
            bf16x4 ov;
#pragma unroll
            for (int i = 0; i < 4; ++i) ov[i] = (__bf16)(o[qg][0][gg * 4 + i] * rinv);
            *(bf16x4*)(vrow + gg * 8 + hi * 4) = ov;
#pragma unroll
            for (int i = 0; i < 4; ++i) ov[i] = (__bf16)(o[qg][1][gg * 4 + i] * rinv);
            *(bf16x4*)(vrow + 32 + gg * 8 + hi * 4) = ov;
        }
    }
}

// ---------------------------------------------------------------------------
extern "C" void kernel_launch(void* const* d_in, const int* in_sizes, int n_in,
                              void* d_out, int out_size, void* d_ws, size_t ws_size,
                              hipStream_t stream) {
    const float* x    = (const float*)d_in[0];  // [4,2048,1024]
    const float* Wqkv = (const float*)d_in[1];  // [1024,3072]
    const float* bqkv = (const float*)d_in[2];  // [3072]
    const float* Wo   = (const float*)d_in[3];  // [1024,1024]
    const float* bo   = (const float*)d_in[4];  // [1024]
    float* out = (float*)d_out;                 // [4,2048,1024] f32

    __bf16* xb    = (__bf16*)d_ws;                        // 8192*1024
    __bf16* WqkvT = xb    + (size_t)ROWS * Dq;            // 3072*1024
    __bf16* WoT   = WqkvT + (size_t)QKV_N * Dq;           // 1024*1024
    __bf16* qkvb  = WoT   + (size_t)Dq * Dq;              // 8192*3072
    __bf16* Vt    = qkvb  + (size_t)ROWS * QKV_N;         // 64*64*2048
    __bf16* v2    = xb;                                   // alias (xb dead)

    prep_kernel<<<12288, 256, 0, stream>>>((const float4*)x, (bf16x4*)xb,
                                           Wqkv, WqkvT, Wo, WoT);

    gemm_qkv_kernel<<<dim3(QKV_N / 192, ROWS / 256), 512, 0, stream>>>(
        xb, WqkvT, bqkv, qkvb, Vt);

    attn_kernel<<<dim3(Bq * Hq, Sq / 256), 256, 0, stream>>>(qkvb, Vt, v2);

    gemm_out_kernel<<<dim3(Dq / 128, ROWS / 128), 256, 0, stream>>>(
        v2, WoT, bo, out, ROWS, Dq, Dq);
}